// Round 4
// baseline (125.537 us; speedup 1.0000x reference)
//
#include <hip/hip_runtime.h>

#define BB 8
#define CC 64
#define OO 64
#define NN 16384
#define MMODE 32
#define JJ 128
#define SFAC 64.0f

typedef __attribute__((ext_vector_type(8))) short short8;   // 8 bf16 = 4 VGPRs (MFMA A/B frag)
typedef __attribute__((ext_vector_type(4))) float f32x4;    // MFMA C/D frag

static __device__ __forceinline__ unsigned short f2bf(float f) {
  unsigned u = __float_as_uint(f);
  u += 0x7FFF + ((u >> 16) & 1);   // RTNE
  return (unsigned short)(u >> 16);
}
static __device__ __forceinline__ unsigned pack2(float a, float b) {
  return (unsigned)f2bf(a) | ((unsigned)f2bf(b) << 16);
}
// hardware sin/cos: v_sin_f32/v_cos_f32 take REVOLUTIONS (D = sin(2*pi*S0))
static __device__ __forceinline__ float sin2pi(float x) { return __builtin_amdgcn_sinf(x); }
static __device__ __forceinline__ float cos2pi(float x) { return __builtin_amdgcn_cosf(x); }

// ws layout (floats): ft [B][J][C] at 0 (65536), A [B][O][J] at 65536 (65536)

// ---------------- forward NUFFT: ft[b,j,c] += sum_{n in slab} bas[j,n]*x[c,n] ----------------
// One block per (256-n slab, b); all 64 channels -> bases computed exactly once.
__global__ __launch_bounds__(256) void fwd_kernel(
    const float* __restrict__ x, const float* __restrict__ x_in,
    float* __restrict__ ft) {
  __shared__ __attribute__((aligned(16))) short bas[JJ * 72];  // [j][n] bf16, stride 72 (18.4 KB)
  __shared__ __attribute__((aligned(16))) short xs[64 * 72];   // [c][n] bf16 (9.2 KB)
  __shared__ __attribute__((aligned(16))) float ps[512];       // x_in slab [256 n][2] (2 KB)
  const int t = threadIdx.x;
  const int b = blockIdx.y, sl = blockIdx.x;
  const int n0 = sl * 256;

  if (t < 128) {  // stage coords for whole slab (coalesced)
    const float4 v = *(const float4*)&x_in[((size_t)b * NN + n0) * 2 + t * 4];
    *(float4*)&ps[t * 4] = v;
  }
  // x loader: 64 c rows x 64 n per micro-slab, 4 float4/thread
  const int xc = t >> 2, xq = t & 3;
  const float* xbase = x + ((size_t)(b * CC + xc)) * NN + n0;
  float4 cur[4];
#pragma unroll
  for (int k = 0; k < 4; ++k) cur[k] = *(const float4*)&xbase[(k * 4 + xq) * 4];

  const int w = t >> 6, L = t & 63;
  const int q4 = L >> 4, l15 = L & 15;
  f32x4 acc[8];
#pragma unroll
  for (int i = 0; i < 8; ++i) acc[i] = (f32x4){0.f, 0.f, 0.f, 0.f};

  __syncthreads();  // ps visible

  for (int s = 0; s < 4; ++s) {
    // ---- stage x micro-slab (fp32 regs -> bf16 LDS) ----
#pragma unroll
    for (int k = 0; k < 4; ++k)
      *(uint2*)&xs[xc * 72 + (k * 4 + xq) * 4] =
          make_uint2(pack2(cur[k].x, cur[k].y), pack2(cur[k].z, cur[k].w));
    if (s < 3) {  // prefetch next micro-slab (overlaps basis gen + MFMA)
#pragma unroll
      for (int k = 0; k < 4; ++k)
        cur[k] = *(const float4*)&xbase[(s + 1) * 64 + (k * 4 + xq) * 4];
    }
    // ---- basis gen: exp(-i*2pi*m*p), revolutions-native HW sin/cos ----
#pragma unroll
    for (int ti = 0; ti < 2; ++ti) {
      const int tau = t + ti * 256;
      const int ng = tau & 7, mm = tau >> 3;
      const int br = mm >> 5, m = mm & 31;
      const float fm = (float)m;
      union { unsigned short u[8]; uint4 v; } R, I;
#pragma unroll
      for (int k = 0; k < 8; ++k) {
        const float p = ps[(s * 64 + ng * 8 + k) * 2 + br];
        float rev = fm * p;
        rev -= floorf(rev);
        R.u[k] = f2bf(cos2pi(rev));   // real = cos(2pi m p)
        I.u[k] = f2bf(-sin2pi(rev));  // imag = -sin(2pi m p)
      }
      const int row = br * 64 + 2 * m;
      *(uint4*)&bas[row * 72 + ng * 8]       = R.v;
      *(uint4*)&bas[(row + 1) * 72 + ng * 8] = I.v;
    }
    __syncthreads();
    // ---- MFMA: wave w owns j-tiles {2w,2w+1} x c-tiles {0..3} ----
#pragma unroll
    for (int ks = 0; ks < 2; ++ks) {
      const int ko = ks * 32 + q4 * 8;
      const short8 a0 = *(const short8*)&bas[(w * 32 + l15) * 72 + ko];
      const short8 a1 = *(const short8*)&bas[(w * 32 + 16 + l15) * 72 + ko];
#pragma unroll
      for (int ct = 0; ct < 4; ++ct) {
        const short8 bv = *(const short8*)&xs[(ct * 16 + l15) * 72 + ko];
        acc[ct]     = __builtin_amdgcn_mfma_f32_16x16x32_bf16(a0, bv, acc[ct], 0, 0, 0);
        acc[4 + ct] = __builtin_amdgcn_mfma_f32_16x16x32_bf16(a1, bv, acc[4 + ct], 0, 0, 0);
      }
    }
    __syncthreads();
  }
  // ---- epilogue: atomics into L2-resident ft. C/D: col(c)=lane&15, row(j)=q4*4+reg ----
#pragma unroll
  for (int ai = 0; ai < 2; ++ai)
#pragma unroll
    for (int ct = 0; ct < 4; ++ct) {
      const f32x4 v = acc[ai * 4 + ct];
#pragma unroll
      for (int r = 0; r < 4; ++r)
        atomicAdd(&ft[((size_t)b * JJ + w * 32 + ai * 16 + q4 * 4 + r) * CC + ct * 16 + l15], v[r]);
    }
}

// ---------------- mode mixing ----------------
__global__ __launch_bounds__(256) void mix_kernel(
    const float* __restrict__ ft, const float* __restrict__ w1,
    const float* __restrict__ w2, float* __restrict__ A) {
  __shared__ float red[8][64];
  __shared__ float fre[64], fim[64];
  const int m = blockIdx.x, branch = blockIdx.y, b = blockIdx.z;
  const int t = threadIdx.x;
  const int c = t & 63, g = t >> 6;
  const int jb = branch * 64 + 2 * m;
  if (t < 64) fre[t] = ft[((size_t)b * JJ + jb) * CC + t];
  else if (t < 128) fim[t - 64] = ft[((size_t)b * JJ + jb + 1) * CC + (t - 64)];
  __syncthreads();
  // complex GEMV over i, split 4 ways across wave groups
  const float* w = branch ? w2 : w1;  // [i][o][m][2]
  float ar = 0.f, ai = 0.f;
#pragma unroll 4
  for (int ii = 0; ii < 16; ++ii) {
    const int i = g * 16 + ii;
    const float2 wv = *(const float2*)&w[(((size_t)i * 64 + c) * MMODE + m) * 2];
    ar += fre[i] * wv.x - fim[i] * wv.y;
    ai += fre[i] * wv.y + fim[i] * wv.x;
  }
  red[g * 2][c] = ar;
  red[g * 2 + 1][c] = ai;
  __syncthreads();
  if (t < 64) {
    const float sr = red[0][t] + red[2][t] + red[4][t] + red[6][t];
    const float si = red[1][t] + red[3][t] + red[5][t] + red[7][t];
    // fold scale S=64 and Re(): out = A_re*cos + A_im*sin
    *(float2*)&A[((size_t)b * OO + t) * JJ + jb] = make_float2(SFAC * sr, -SFAC * si);
  }
}

// ---------------- inverse NUFFT: out[b,o,n] = sum_j A2[o,j] * bas[n,j] ----------------
__global__ __launch_bounds__(256) void inv_kernel(
    const float* __restrict__ x_out, const float* __restrict__ A,
    float* __restrict__ out) {
  __shared__ __attribute__((aligned(16))) short As_s[OO * 136];  // [o][j] bf16, stride 136
  __shared__ __attribute__((aligned(16))) short basn[64 * 136];  // [n][j] bf16
  __shared__ __attribute__((aligned(16))) float psI[512];        // x_out slab [256 n][2]
  const int t = threadIdx.x;
  const int b = blockIdx.y;
  const int n0 = blockIdx.x * 256;

  if (t < 128) {
    const float4 v = *(const float4*)&x_out[((size_t)b * NN + n0) * 2 + t * 4];
    *(float4*)&psI[t * 4] = v;
  }
#pragma unroll
  for (int idx = t; idx < 2048; idx += 256) {   // A fp32 -> bf16 LDS, coalesced
    const int o = idx >> 5, j4 = idx & 31;
    const float4 v = *(const float4*)&A[((size_t)b * OO + o) * JJ + j4 * 4];
    *(uint2*)&As_s[o * 136 + j4 * 4] = make_uint2(pack2(v.x, v.y), pack2(v.z, v.w));
  }
  const int w = t >> 6, L = t & 63;
  const int q4 = L >> 4, l15 = L & 15;
  const int nl = t & 63, q = t >> 6, br = q >> 1, half = q & 1;
  const int ot0 = (w & 1) * 32;   // o rows: ot0 + {0..15, 16..31}
  const int nt0 = (w >> 1) * 32;  // n cols: nt0 + {0..15, 16..31}
  __syncthreads();

  for (int s = 0; s < 4; ++s) {
    // ---- basis gen: lane owns row n; exp(+i*2pi*m*p) by recurrence over m ----
    {
      const float p = psI[(s * 64 + nl) * 2 + br];
      const float fr = p - floorf(p);
      const float s1 = sin2pi(fr), c1 = cos2pi(fr);   // step = exp(+i*2pi*p)
      float brr = 1.f, bii = 0.f;
      if (half) {  // start at step^16 via 4 squarings
        float r = c1, qq = s1;
#pragma unroll
        for (int k = 0; k < 4; ++k) { const float nr = r*r - qq*qq, ni = 2.f*r*qq; r = nr; qq = ni; }
        brr = r; bii = qq;
      }
      short* bp = &basn[nl * 136 + br * 64 + half * 32];
#pragma unroll
      for (int g = 0; g < 4; ++g) {
        union { unsigned short u[8]; uint4 v; } P;
#pragma unroll
        for (int mi = 0; mi < 4; ++mi) {
          P.u[2 * mi]     = f2bf(brr);
          P.u[2 * mi + 1] = f2bf(bii);
          const float nr = brr * c1 - bii * s1, ni = brr * s1 + bii * c1;
          brr = nr; bii = ni;
        }
        *(uint4*)&bp[g * 8] = P.v;
      }
    }
    __syncthreads();
    f32x4 acc[4];
#pragma unroll
    for (int i = 0; i < 4; ++i) acc[i] = (f32x4){0.f, 0.f, 0.f, 0.f};
#pragma unroll
    for (int ks = 0; ks < 4; ++ks) {
      const int ko = ks * 32 + q4 * 8;
      const short8 a0 = *(const short8*)&As_s[(ot0 + l15) * 136 + ko];
      const short8 a1 = *(const short8*)&As_s[(ot0 + 16 + l15) * 136 + ko];
      const short8 b0 = *(const short8*)&basn[(nt0 + l15) * 136 + ko];
      const short8 b1 = *(const short8*)&basn[(nt0 + 16 + l15) * 136 + ko];
      acc[0] = __builtin_amdgcn_mfma_f32_16x16x32_bf16(a0, b0, acc[0], 0, 0, 0);
      acc[1] = __builtin_amdgcn_mfma_f32_16x16x32_bf16(a0, b1, acc[1], 0, 0, 0);
      acc[2] = __builtin_amdgcn_mfma_f32_16x16x32_bf16(a1, b0, acc[2], 0, 0, 0);
      acc[3] = __builtin_amdgcn_mfma_f32_16x16x32_bf16(a1, b1, acc[3], 0, 0, 0);
    }
    // ---- store: row o = ot0+oi*16+q4*4+r, col n = nt0+ni*16+l15 (64B segments) ----
    const int nbase = n0 + s * 64 + nt0 + l15;
#pragma unroll
    for (int oi = 0; oi < 2; ++oi)
#pragma unroll
      for (int ni = 0; ni < 2; ++ni) {
        const f32x4 v = acc[oi * 2 + ni];
#pragma unroll
        for (int r = 0; r < 4; ++r)
          out[((size_t)b * OO + ot0 + oi * 16 + q4 * 4 + r) * NN + nbase + ni * 16] = v[r];
      }
    __syncthreads();
  }
}

extern "C" void kernel_launch(void* const* d_in, const int* in_sizes, int n_in,
                              void* d_out, int out_size, void* d_ws, size_t ws_size,
                              hipStream_t stream) {
  const float* x     = (const float*)d_in[0];
  const float* x_in  = (const float*)d_in[1];
  const float* x_out = (const float*)d_in[2];
  const float* w1    = (const float*)d_in[3];
  const float* w2    = (const float*)d_in[4];
  float* out = (float*)d_out;
  float* ft = (float*)d_ws;                  // [B][J][C], 256 KB, L2-resident
  float* A  = ft + (size_t)BB * JJ * CC;     // [B][O][J]

  hipMemsetAsync(ft, 0, (size_t)BB * JJ * CC * sizeof(float), stream);
  fwd_kernel<<<dim3(64, BB), 256, 0, stream>>>(x, x_in, ft);
  mix_kernel<<<dim3(MMODE, 2, BB), 256, 0, stream>>>(ft, w1, w2, A);
  inv_kernel<<<dim3(64, BB), 256, 0, stream>>>(x_out, A, out);
}